// Round 12
// baseline (170.185 us; speedup 1.0000x reference)
//
#include <hip/hip_runtime.h>
#include <stdint.h>

#define N1 8192
#define N2 8192
#define DK 128
#define TAU 0.08f     // repair margin (sim units); ~23 sigma of single-f16 dot noise

typedef _Float16 half8 __attribute__((ext_vector_type(8)));
typedef _Float16 half4 __attribute__((ext_vector_type(4)));
typedef float floatx4 __attribute__((ext_vector_type(4)));

// Module-scope device scratch (graph-capture safe). Fully rewritten each launch.
__device__ __align__(16) _Float16 g_Af[N1 * DK];         // 2 MB
__device__ __align__(16) _Float16 g_Bf[N2 * DK];         // 2 MB
__device__ __align__(16) uint2 g_rowtop2[128 * N1];      // 8 MB [64colgrp][row] wave-owned
__device__ __align__(16) uint2 g_coltop2[128 * N2];      // 8 MB [64rowgrp][col]
__device__ int g_nn12[N1];
__device__ int g_nn21[N2];
__device__ unsigned g_done;                               // reset by convert each launch

// order-preserving f32 <-> u32
__device__ __forceinline__ unsigned mono32(float v) {
    unsigned u = __float_as_uint(v);
    return u ^ ((u & 0x80000000u) ? 0xFFFFFFFFu : 0x80000000u);
}
__device__ __forceinline__ float unmono32(unsigned k) {
    unsigned u = (k & 0x80000000u) ? (k ^ 0x80000000u) : ~k;
    return __uint_as_float(u);
}
// key: monotone value bits, low 7 bits = idx within 64-group (quant ~6e-4 << TAU)
__device__ __forceinline__ unsigned qkey(float v, unsigned idx) {
    return (mono32(v) & 0xFFFFFF80u) | idx;
}
__device__ __forceinline__ void push2u(unsigned& t1, unsigned& t2, unsigned p) {
    unsigned lo = min(t1, p);
    t1 = max(t1, p);
    t2 = max(t2, lo);
}
__device__ __forceinline__ void merge2u(unsigned& t1, unsigned& t2, unsigned o1, unsigned o2) {
    unsigned n1 = max(t1, o1);
    unsigned n2 = max(min(t1, o1), max(t2, o2));
    t1 = n1; t2 = n2;
}
__device__ __forceinline__ unsigned long long pack64(float d, unsigned idx) {
    return ((unsigned long long)mono32(d) << 32) | (unsigned)(~idx);
}

// fp32 -> f16 direct (repair pass handles near-ties). Also resets g_done.
__global__ __launch_bounds__(256) void convert_kernel(const float* __restrict__ A,
                                                      const float* __restrict__ B) {
    if (blockIdx.x == 0 && threadIdx.x == 0) g_done = 0u;
    int t = blockIdx.x * blockDim.x + threadIdx.x;
    const int perMat = N1 * (DK / 4);
    int which = (t >= perMat) ? 1 : 0;
    const float* src = which ? B : A;
    _Float16* dst = which ? g_Bf : g_Af;
    int i = which ? t - perMat : t;
    int m = i >> 5;
    int kq = i & 31;
    float4 v = *reinterpret_cast<const float4*>(src + (size_t)m * DK + kq * 4);
    half4 h = {(_Float16)v.x, (_Float16)v.y, (_Float16)v.z, (_Float16)v.w};
    *reinterpret_cast<half4*>(dst + (size_t)m * DK + kq * 4) = h;
}

// 128x128 tile per block, 4 waves. No LDS, no __syncthreads: each wave writes
// its own 64-group top2 runs directly. (R11-proven, byte-identical.)
__global__ __launch_bounds__(256) void simf16_kernel() {
    const int tid  = threadIdx.x;
    const int lane = tid & 63;
    const int wave = tid >> 6;
    const int wm = wave >> 1, wn = wave & 1;
    const int tx = blockIdx.x, ty = blockIdx.y;
    const int row0 = ty * 128, col0 = tx * 128;
    const int fr = lane & 15, q = lane >> 4;

    floatx4 acc[4][4];
#pragma unroll
    for (int mt = 0; mt < 4; ++mt)
#pragma unroll
        for (int nt = 0; nt < 4; ++nt)
            acc[mt][nt] = (floatx4){0.f, 0.f, 0.f, 0.f};

    const _Float16* Ab = g_Af + (size_t)(row0 + wm * 64 + fr) * DK + q * 8;
    const _Float16* Bb = g_Bf + (size_t)(col0 + wn * 64 + fr) * DK + q * 8;

#pragma unroll
    for (int ks = 0; ks < 4; ++ks) {
        half8 af[4], bf[4];
#pragma unroll
        for (int mt = 0; mt < 4; ++mt)
            af[mt] = *reinterpret_cast<const half8*>(Ab + mt * 16 * DK + ks * 32);
#pragma unroll
        for (int nt = 0; nt < 4; ++nt)
            bf[nt] = *reinterpret_cast<const half8*>(Bb + nt * 16 * DK + ks * 32);
#pragma unroll
        for (int mt = 0; mt < 4; ++mt)
#pragma unroll
            for (int nt = 0; nt < 4; ++nt)
                acc[mt][nt] = __builtin_amdgcn_mfma_f32_16x16x32_f16(af[mt], bf[nt], acc[mt][nt], 0, 0, 0);
    }

    // row phase: top2 over this wave's 64 cols (C/D: col=lane&15, row=q*4+reg)
#pragma unroll
    for (int mt = 0; mt < 4; ++mt) {
#pragma unroll
        for (int reg = 0; reg < 4; ++reg) {
            unsigned t1 = 0u, t2 = 0u;
#pragma unroll
            for (int nt = 0; nt < 4; ++nt)
                push2u(t1, t2, qkey(acc[mt][nt][reg], (unsigned)(nt * 16 + fr)));
#pragma unroll
            for (int off = 1; off < 16; off <<= 1) {
                unsigned o1 = __shfl_xor(t1, off, 64);
                unsigned o2 = __shfl_xor(t2, off, 64);
                merge2u(t1, t2, o1, o2);
            }
            if (fr == 0) {
                int grp = tx * 2 + wn;
                int r = row0 + wm * 64 + mt * 16 + q * 4 + reg;
                g_rowtop2[(size_t)grp * N1 + r] = make_uint2(t1, t2);
            }
        }
    }
    // col phase: top2 over this wave's 64 rows
#pragma unroll
    for (int nt = 0; nt < 4; ++nt) {
        unsigned t1 = 0u, t2 = 0u;
#pragma unroll
        for (int mt = 0; mt < 4; ++mt)
#pragma unroll
            for (int reg = 0; reg < 4; ++reg)
                push2u(t1, t2, qkey(acc[mt][nt][reg], (unsigned)(mt * 16 + q * 4 + reg)));
        unsigned o1 = __shfl_xor(t1, 16, 64), o2 = __shfl_xor(t2, 16, 64);
        merge2u(t1, t2, o1, o2);
        o1 = __shfl_xor(t1, 32, 64); o2 = __shfl_xor(t2, 32, 64);
        merge2u(t1, t2, o1, o2);
        if (q == 0) {
            int grp = ty * 2 + wm;
            int c = col0 + wn * 64 + nt * 16 + fr;
            g_coltop2[(size_t)grp * N2 + c] = make_uint2(t1, t2);
        }
    }
}

// 1024 blocks: 0..511 repair cols (write g_nn21), 512..1023 repair rows
// (write g_nn12 + exact scores). Candidates within TAU of approx max get the
// fp32 SEQUENTIAL k-ascending fmaf chain (bitwise reference rounding, R6-proven).
// Last-finishing block (device-scope fence+counter handshake) runs the mutual
// check over all rows — dispatch-order independent, no spinning, no deadlock.
__global__ __launch_bounds__(256) void fix_kernel(const float* __restrict__ A,
                                                  const float* __restrict__ B,
                                                  float* __restrict__ out) {
    __shared__ uint2 tile[128 * 16];          // 16 KB
    __shared__ unsigned long long slot[16];
    __shared__ int cand[256];
    __shared__ int cand_cnt;
    __shared__ bool last;

    const int tid = threadIdx.x;
    const bool rowside = blockIdx.x >= 512;
    const int base0 = (blockIdx.x & 511) * 16;
    const uint2* top2 = rowside ? g_rowtop2 : g_coltop2;

#pragma unroll
    for (int i = 0; i < 8; ++i) {
        int idx = i * 256 + tid;              // 0..2047
        int grp = idx >> 4, c = idx & 15;
        tile[grp * 16 + c] = top2[(size_t)grp * N1 + base0 + c];
    }
    if (tid < 16) slot[tid] = 0ULL;
    if (tid == 0) cand_cnt = 0;
    __syncthreads();

    const int c = tid >> 4, j = tid & 15;     // 16 threads per row/col
    float mx = -1e30f;
#pragma unroll
    for (int s = 0; s < 8; ++s) {
        uint2 e = tile[(j * 8 + s) * 16 + c];
        mx = fmaxf(mx, unmono32(e.x & 0xFFFFFF80u));
    }
    mx = fmaxf(mx, __shfl_xor(mx, 1, 64));
    mx = fmaxf(mx, __shfl_xor(mx, 2, 64));
    mx = fmaxf(mx, __shfl_xor(mx, 4, 64));
    mx = fmaxf(mx, __shfl_xor(mx, 8, 64));
    const float thr = mx - TAU;
#pragma unroll
    for (int s = 0; s < 8; ++s) {
        int grp = j * 8 + s;
        uint2 e = tile[grp * 16 + c];
        if (unmono32(e.x & 0xFFFFFF80u) >= thr) {
            int o = grp * 64 + (int)(e.x & 127u);
            int si = atomicAdd(&cand_cnt, 1);
            if (si < 256) cand[si] = (c << 16) | o;
        }
        if (unmono32(e.y & 0xFFFFFF80u) >= thr) {
            int o = grp * 64 + (int)(e.y & 127u);
            int si = atomicAdd(&cand_cnt, 1);
            if (si < 256) cand[si] = (c << 16) | o;
        }
    }
    __syncthreads();

    const int nc = min(cand_cnt, 256);
    for (int i = tid; i < nc; i += 256) {
        int pc = cand[i];
        int cl = pc >> 16, other = pc & 0xFFFF;
        const float* ar = rowside ? (A + (size_t)(base0 + cl) * DK) : (A + (size_t)other * DK);
        const float* br = rowside ? (B + (size_t)other * DK) : (B + (size_t)(base0 + cl) * DK);
        float d = 0.0f;
#pragma unroll
        for (int k4 = 0; k4 < DK / 4; ++k4) {
            float4 a = *reinterpret_cast<const float4*>(ar + k4 * 4);
            float4 b = *reinterpret_cast<const float4*>(br + k4 * 4);
            d = fmaf(a.x, b.x, d);
            d = fmaf(a.y, b.y, d);
            d = fmaf(a.z, b.z, d);
            d = fmaf(a.w, b.w, d);
        }
        atomicMax(&slot[cl], pack64(d, (unsigned)other));
    }
    __syncthreads();

    if (tid < 16) {
        unsigned long long p = slot[tid];
        int idx = base0 + tid;
        if (rowside) {
            g_nn12[idx] = (int)(~(unsigned)p);
            out[N1 + idx] = unmono32((unsigned)(p >> 32));   // exact score
        } else {
            g_nn21[idx] = (int)(~(unsigned)p);
        }
    }

    // ---- last-finisher mutual check ----
    __syncthreads();
    if (tid == 0) {
        __threadfence();                       // release g_nn12/g_nn21 writes
        unsigned old = atomicAdd(&g_done, 1u);
        last = (old == 1023u);
    }
    __syncthreads();
    if (last) {
        __threadfence();                       // acquire all blocks' writes
        for (int i = tid; i < N1; i += 256) {
            int m = g_nn12[i];
            out[i] = (float)((g_nn21[m] == i) ? m : -1);     // matches0
        }
    }
}

extern "C" void kernel_launch(void* const* d_in, const int* in_sizes, int n_in,
                              void* d_out, int out_size, void* d_ws, size_t ws_size,
                              hipStream_t stream) {
    const float* A = (const float*)d_in[0];   // desc1 [8192,128] f32
    const float* B = (const float*)d_in[1];   // desc2 [8192,128] f32
    float* out = (float*)d_out;               // [0:8192]=matches, [8192:16384]=scores

    convert_kernel<<<2 * N1 * (DK / 4) / 256, 256, 0, stream>>>(A, B);
    dim3 grid(N2 / 128, N1 / 128);
    simf16_kernel<<<grid, 256, 0, stream>>>();
    fix_kernel<<<1024, 256, 0, stream>>>(A, B, out);
}

// Round 13
// 141.887 us; speedup vs baseline: 1.1994x; 1.1994x over previous
//
#include <hip/hip_runtime.h>
#include <stdint.h>

#define N1 8192
#define N2 8192
#define DK 128
#define TAU 0.08f     // repair margin (sim units); ~23 sigma of single-f16 dot noise

typedef _Float16 half8 __attribute__((ext_vector_type(8)));
typedef _Float16 half4 __attribute__((ext_vector_type(4)));
typedef float floatx4 __attribute__((ext_vector_type(4)));

// Module-scope device scratch (graph-capture safe). Fully rewritten each launch.
__device__ __align__(16) _Float16 g_Af[N1 * DK];        // 2 MB
__device__ __align__(16) _Float16 g_Bf[N2 * DK];        // 2 MB
__device__ __align__(16) uint2 g_rowtop2[64 * N1];      // 4 MB [128colgrp][row] tile-owned
__device__ __align__(16) uint2 g_coltop2[64 * N2];      // 4 MB [128rowgrp][col]
__device__ int g_nn21[N2];

// order-preserving f32 <-> u32
__device__ __forceinline__ unsigned mono32(float v) {
    unsigned u = __float_as_uint(v);
    return u ^ ((u & 0x80000000u) ? 0xFFFFFFFFu : 0x80000000u);
}
__device__ __forceinline__ float unmono32(unsigned k) {
    unsigned u = (k & 0x80000000u) ? (k ^ 0x80000000u) : ~k;
    return __uint_as_float(u);
}
// key: monotone value bits, low 7 bits = idx within 128-group (quant ~6e-4 << TAU)
__device__ __forceinline__ unsigned qkey(float v, unsigned idx) {
    return (mono32(v) & 0xFFFFFF80u) | idx;
}
__device__ __forceinline__ void push2u(unsigned& t1, unsigned& t2, unsigned p) {
    unsigned lo = min(t1, p);
    t1 = max(t1, p);
    t2 = max(t2, lo);
}
__device__ __forceinline__ void merge2u(unsigned& t1, unsigned& t2, unsigned o1, unsigned o2) {
    unsigned n1 = max(t1, o1);
    unsigned n2 = max(min(t1, o1), max(t2, o2));
    t1 = n1; t2 = n2;
}
__device__ __forceinline__ unsigned long long pack64(float d, unsigned idx) {
    return ((unsigned long long)mono32(d) << 32) | (unsigned)(~idx);
}

// fp32 -> f16 direct (repair pass handles near-ties).
__global__ __launch_bounds__(256) void convert_kernel(const float* __restrict__ A,
                                                      const float* __restrict__ B) {
    int t = blockIdx.x * blockDim.x + threadIdx.x;
    const int perMat = N1 * (DK / 4);
    int which = (t >= perMat) ? 1 : 0;
    const float* src = which ? B : A;
    _Float16* dst = which ? g_Bf : g_Af;
    int i = which ? t - perMat : t;
    int m = i >> 5;
    int kq = i & 31;
    float4 v = *reinterpret_cast<const float4*>(src + (size_t)m * DK + kq * 4);
    half4 h = {(_Float16)v.x, (_Float16)v.y, (_Float16)v.z, (_Float16)v.w};
    *reinterpret_cast<half4*>(dst + (size_t)m * DK + kq * 4) = h;
}

// 128x128 tile per block, 4 waves, direct-global MFMA fragments (R11-proven),
// cross-wave LDS-merged 128-group top2 epilogue (R8-proven), XCD-aware tile
// swizzle, and min-waves=4 occupancy bound (cap 128 VGPR; acc 64 + frags 32
// should fit — watch VGPR_Count/FETCH for spill evidence).
__global__ __launch_bounds__(256, 4) void simf16_kernel() {
    __shared__ uint2 lmerge[2][128];   // 2 KB

    const int tid  = threadIdx.x;
    const int lane = tid & 63;
    const int wave = tid >> 6;
    const int wm = wave >> 1, wn = wave & 1;
    const int fr = lane & 15, q = lane >> 4;

    // XCD swizzle: dispatch-neighbors (round-robin over 8 XCDs) get same ty
    // and clustered tx -> per-XCD L2 panel reuse.
    const int flat = blockIdx.y * 64 + blockIdx.x;
    const int xcd = flat & 7;
    const int j = flat >> 3;
    const int ty = j >> 3;
    const int tx = ((j & 7) << 3) | xcd;
    const int row0 = ty * 128, col0 = tx * 128;

    floatx4 acc[4][4];
#pragma unroll
    for (int mt = 0; mt < 4; ++mt)
#pragma unroll
        for (int nt = 0; nt < 4; ++nt)
            acc[mt][nt] = (floatx4){0.f, 0.f, 0.f, 0.f};

    const size_t abase = (size_t)(row0 + wm * 64 + fr) * DK + q * 8;
    const size_t bbase = (size_t)(col0 + wn * 64 + fr) * DK + q * 8;

#pragma unroll
    for (int ks = 0; ks < 4; ++ks) {
        half8 af[4], bf[4];
#pragma unroll
        for (int mt = 0; mt < 4; ++mt)
            af[mt] = *reinterpret_cast<const half8*>(g_Af + abase + mt * 16 * DK + ks * 32);
#pragma unroll
        for (int nt = 0; nt < 4; ++nt)
            bf[nt] = *reinterpret_cast<const half8*>(g_Bf + bbase + nt * 16 * DK + ks * 32);
#pragma unroll
        for (int mt = 0; mt < 4; ++mt)
#pragma unroll
            for (int nt = 0; nt < 4; ++nt)
                acc[mt][nt] = __builtin_amdgcn_mfma_f32_16x16x32_f16(af[mt], bf[nt], acc[mt][nt], 0, 0, 0);
    }

    // ---- row phase: top2 over 128 cols (C/D: col=lane&15, row=q*4+reg) ----
#pragma unroll
    for (int mt = 0; mt < 4; ++mt) {
#pragma unroll
        for (int reg = 0; reg < 4; ++reg) {
            unsigned t1 = 0u, t2 = 0u;
#pragma unroll
            for (int nt = 0; nt < 4; ++nt)
                push2u(t1, t2, qkey(acc[mt][nt][reg], (unsigned)(wn * 64 + nt * 16 + fr)));
#pragma unroll
            for (int off = 1; off < 16; off <<= 1) {
                unsigned o1 = __shfl_xor(t1, off, 64);
                unsigned o2 = __shfl_xor(t2, off, 64);
                merge2u(t1, t2, o1, o2);
            }
            if (fr == 0) lmerge[wn][wm * 64 + mt * 16 + q * 4 + reg] = make_uint2(t1, t2);
        }
    }
    __syncthreads();
    if (tid < 128) {
        uint2 a = lmerge[0][tid], b = lmerge[1][tid];
        merge2u(a.x, a.y, b.x, b.y);
        g_rowtop2[(size_t)tx * N1 + row0 + tid] = a;   // contiguous 1 KB run
    }
    __syncthreads();

    // ---- col phase: top2 over 128 rows ----
#pragma unroll
    for (int nt = 0; nt < 4; ++nt) {
        unsigned t1 = 0u, t2 = 0u;
#pragma unroll
        for (int mt = 0; mt < 4; ++mt)
#pragma unroll
            for (int reg = 0; reg < 4; ++reg)
                push2u(t1, t2, qkey(acc[mt][nt][reg], (unsigned)(wm * 64 + mt * 16 + q * 4 + reg)));
        unsigned o1 = __shfl_xor(t1, 16, 64), o2 = __shfl_xor(t2, 16, 64);
        merge2u(t1, t2, o1, o2);
        o1 = __shfl_xor(t1, 32, 64); o2 = __shfl_xor(t2, 32, 64);
        merge2u(t1, t2, o1, o2);
        if (q == 0) lmerge[wm][wn * 64 + nt * 16 + fr] = make_uint2(t1, t2);
    }
    __syncthreads();
    if (tid < 128) {
        uint2 a = lmerge[0][tid], b = lmerge[1][tid];
        merge2u(a.x, a.y, b.x, b.y);
        g_coltop2[(size_t)ty * N2 + col0 + tid] = a;
    }
}

// 16 cols per block (512 blocks). Candidates within TAU of approx max get the
// fp32 SEQUENTIAL k-ascending fmaf chain (bitwise reference rounding, R6-proven).
__global__ __launch_bounds__(256) void colfix_kernel(const float* __restrict__ A,
                                                     const float* __restrict__ B) {
    __shared__ uint2 tile[64 * 16];           // 8 KB
    __shared__ unsigned long long slot[16];
    __shared__ int cand[256];
    __shared__ int cand_cnt;

    const int tid = threadIdx.x;
    const int c0 = blockIdx.x * 16;

#pragma unroll
    for (int i = 0; i < 4; ++i) {
        int idx = i * 256 + tid;              // 0..1023
        int grp = idx >> 4, c = idx & 15;
        tile[grp * 16 + c] = g_coltop2[(size_t)grp * N2 + c0 + c];
    }
    if (tid < 16) slot[tid] = 0ULL;
    if (tid == 0) cand_cnt = 0;
    __syncthreads();

    const int c = tid >> 4, j = tid & 15;     // 16 threads per col, 4 grps each
    float mx = -1e30f;
#pragma unroll
    for (int s = 0; s < 4; ++s) {
        uint2 e = tile[(j * 4 + s) * 16 + c];
        mx = fmaxf(mx, unmono32(e.x & 0xFFFFFF80u));
    }
    mx = fmaxf(mx, __shfl_xor(mx, 1, 64));
    mx = fmaxf(mx, __shfl_xor(mx, 2, 64));
    mx = fmaxf(mx, __shfl_xor(mx, 4, 64));
    mx = fmaxf(mx, __shfl_xor(mx, 8, 64));
    const float thr = mx - TAU;
#pragma unroll
    for (int s = 0; s < 4; ++s) {
        int grp = j * 4 + s;
        uint2 e = tile[grp * 16 + c];
        if (unmono32(e.x & 0xFFFFFF80u) >= thr) {
            int rr = grp * 128 + (int)(e.x & 127u);
            int si = atomicAdd(&cand_cnt, 1);
            if (si < 256) cand[si] = (c << 16) | rr;
        }
        if (unmono32(e.y & 0xFFFFFF80u) >= thr) {
            int rr = grp * 128 + (int)(e.y & 127u);
            int si = atomicAdd(&cand_cnt, 1);
            if (si < 256) cand[si] = (c << 16) | rr;
        }
    }
    __syncthreads();

    const int nc = min(cand_cnt, 256);
    for (int i = tid; i < nc; i += 256) {
        int pc = cand[i];
        int cl = pc >> 16, rr = pc & 0xFFFF;
        const float* ar = A + (size_t)rr * DK;
        const float* br = B + (size_t)(c0 + cl) * DK;
        float d = 0.0f;
#pragma unroll
        for (int k4 = 0; k4 < DK / 4; ++k4) {
            float4 a = *reinterpret_cast<const float4*>(ar + k4 * 4);
            float4 b = *reinterpret_cast<const float4*>(br + k4 * 4);
            d = fmaf(a.x, b.x, d);
            d = fmaf(a.y, b.y, d);
            d = fmaf(a.z, b.z, d);
            d = fmaf(a.w, b.w, d);
        }
        atomicMax(&slot[cl], pack64(d, (unsigned)rr));
    }
    __syncthreads();

    if (tid < 16) g_nn21[c0 + tid] = (int)(~(unsigned)slot[tid]);
}

// 16 rows per block (512 blocks). Same repair; fuses mutual check (g_nn21
// complete from the prior colfix launch) and writes both outputs.
__global__ __launch_bounds__(256) void rowfix_mutual_kernel(const float* __restrict__ A,
                                                            const float* __restrict__ B,
                                                            float* __restrict__ out) {
    __shared__ uint2 tile[64 * 16];
    __shared__ unsigned long long slot[16];
    __shared__ int cand[256];
    __shared__ int cand_cnt;

    const int tid = threadIdx.x;
    const int r0 = blockIdx.x * 16;

#pragma unroll
    for (int i = 0; i < 4; ++i) {
        int idx = i * 256 + tid;
        int grp = idx >> 4, r = idx & 15;
        tile[grp * 16 + r] = g_rowtop2[(size_t)grp * N1 + r0 + r];
    }
    if (tid < 16) slot[tid] = 0ULL;
    if (tid == 0) cand_cnt = 0;
    __syncthreads();

    const int r = tid >> 4, j = tid & 15;
    float mx = -1e30f;
#pragma unroll
    for (int s = 0; s < 4; ++s) {
        uint2 e = tile[(j * 4 + s) * 16 + r];
        mx = fmaxf(mx, unmono32(e.x & 0xFFFFFF80u));
    }
    mx = fmaxf(mx, __shfl_xor(mx, 1, 64));
    mx = fmaxf(mx, __shfl_xor(mx, 2, 64));
    mx = fmaxf(mx, __shfl_xor(mx, 4, 64));
    mx = fmaxf(mx, __shfl_xor(mx, 8, 64));
    const float thr = mx - TAU;
#pragma unroll
    for (int s = 0; s < 4; ++s) {
        int grp = j * 4 + s;
        uint2 e = tile[grp * 16 + r];
        if (unmono32(e.x & 0xFFFFFF80u) >= thr) {
            int cc = grp * 128 + (int)(e.x & 127u);
            int si = atomicAdd(&cand_cnt, 1);
            if (si < 256) cand[si] = (r << 16) | cc;
        }
        if (unmono32(e.y & 0xFFFFFF80u) >= thr) {
            int cc = grp * 128 + (int)(e.y & 127u);
            int si = atomicAdd(&cand_cnt, 1);
            if (si < 256) cand[si] = (r << 16) | cc;
        }
    }
    __syncthreads();

    const int nc = min(cand_cnt, 256);
    for (int i = tid; i < nc; i += 256) {
        int pc = cand[i];
        int rl = pc >> 16, cc = pc & 0xFFFF;
        const float* ar = A + (size_t)(r0 + rl) * DK;
        const float* br = B + (size_t)cc * DK;
        float d = 0.0f;
#pragma unroll
        for (int k4 = 0; k4 < DK / 4; ++k4) {
            float4 a = *reinterpret_cast<const float4*>(ar + k4 * 4);
            float4 b = *reinterpret_cast<const float4*>(br + k4 * 4);
            d = fmaf(a.x, b.x, d);
            d = fmaf(a.y, b.y, d);
            d = fmaf(a.z, b.z, d);
            d = fmaf(a.w, b.w, d);
        }
        atomicMax(&slot[rl], pack64(d, (unsigned)cc));
    }
    __syncthreads();

    if (tid < 16) {
        unsigned long long p = slot[tid];
        int row = r0 + tid;
        int m = (int)(~(unsigned)p);
        out[row] = (float)((g_nn21[m] == row) ? m : -1);     // matches0
        out[N1 + row] = unmono32((unsigned)(p >> 32));       // exact score
    }
}

extern "C" void kernel_launch(void* const* d_in, const int* in_sizes, int n_in,
                              void* d_out, int out_size, void* d_ws, size_t ws_size,
                              hipStream_t stream) {
    const float* A = (const float*)d_in[0];   // desc1 [8192,128] f32
    const float* B = (const float*)d_in[1];   // desc2 [8192,128] f32
    float* out = (float*)d_out;               // [0:8192]=matches, [8192:16384]=scores

    convert_kernel<<<2 * N1 * (DK / 4) / 256, 256, 0, stream>>>(A, B);
    dim3 grid(64, 64);
    simf16_kernel<<<grid, 256, 0, stream>>>();
    colfix_kernel<<<N2 / 16, 256, 0, stream>>>(A, B);
    rowfix_mutual_kernel<<<N1 / 16, 256, 0, stream>>>(A, B, out);
}